// Round 2
// baseline (217.174 us; speedup 1.0000x reference)
//
#include <hip/hip_runtime.h>

// GroupGSDConv round 6: async-staged implicit GEMM, with safety fallback.
// Fast path (ws_size >= ~41.2 MB):
//   gsd_prep: transpose+convert x [B,C,H,W] fp32 -> zero-padded pixel-major
//   xb16 [B][140][140][64] bf16 (pad=6 each side) + merged setup (desc/wpack).
//   gsd_conv<true>: staging = 5 x global_load_lds(16B) per wave per ks (no
//   VALU convert, no LDS write port); bank swizzle f(pix)=(pix>>2)&1 baked
//   into the per-lane GLOBAL source address (LDS dest stays linear, rule #21).
// Fallback (small workspace): gsd_conv<false> = round-4 in-kernel fp32
//   staging (proven correct), upgraded to the same improved swizzle.
// Read side: dws = pix*8 + ((h ^ f(pix))<<2) -> lanes n,n+4 differ by 4
// banks; bank-quad reuse pattern matches consecutive-address b128 (free).
// LDS 40960 B (39424 + tail pad for clamped chunks) -> 2 blocks/CU.

#define HW_ 128
#define C_ 64
#define B_ 16
#define EX 44
#define EY 28
#define NPIX (EY * EX)  // 1232 staged pixels
#define PADW 140
#define MAX_ITEMS 12
#define WS_WPACK_OFF 1024
#define WS_XB16_OFF (1 << 20)
#define XB16_BYTES ((size_t)B_ * PADW * PADW * C_ * 2)  // 40,140,800

// desc layout (ints):
//  [0..63]        perm (sorted-by-dilation channel ids)
//  [64+t]         cnt_t   (items in octile t, t<2)
//  [66+t*6+s]     dilation of item (t,s)
//  [78+t*6+s]     wix (wpack index) of item (t,s)
//  [90]           ni_total

typedef __attribute__((ext_vector_type(8))) short short8;
typedef __attribute__((ext_vector_type(16))) float floatx16;

__device__ __forceinline__ unsigned bf16rne(float f) {
  unsigned u = __float_as_uint(f);
  return (u + 0x7FFFu + ((u >> 16) & 1u)) >> 16;  // round-nearest-even
}

#define GLOAD_LDS16(g, l)                                   \
  __builtin_amdgcn_global_load_lds(                         \
      (const __attribute__((address_space(1))) void*)(g),   \
      (__attribute__((address_space(3))) void*)(l), 16, 0, 0)

__global__ __launch_bounds__(256) void gsd_prep(
    const float* __restrict__ x, const int* __restrict__ offsets,
    const float* __restrict__ w, int* __restrict__ desc,
    uint4* __restrict__ wpack, unsigned short* __restrict__ xb16,
    const int nrow) {
  const int bid = blockIdx.x;
  const int tid = threadIdx.x;

  if (bid < nrow) {
    // ---- transpose+convert one padded row: [C][W] fp32 -> [Wp][C] bf16 ----
    // one row = 140 px * 64 ch * 2 B = 17920 B = 1120 uint4 (8 uint4/px)
    const int b = bid / PADW, py = bid - b * PADW;
    uint4* o4 = (uint4*)(xb16 + (size_t)bid * (PADW * C_));
    const uint4 z = make_uint4(0, 0, 0, 0);
    if (py < 6 || py >= PADW - 6) {
      for (int i = tid; i < PADW * C_ / 8; i += 256) o4[i] = z;
      return;
    }
    // x-pad: px 0..5 -> uint4 0..47, px 134..139 -> uint4 1072..1119
    if (tid < 48) o4[tid] = z;
    else if (tid < 96) o4[1024 + tid] = z;
    const int y = py - 6;
    __shared__ unsigned l32[128 * 33];  // [x][c-pair], +1 pad
    const int xx = tid & 127, ph = tid >> 7;
    const float* xp = x + (size_t)b * (C_ * HW_ * HW_) + y * HW_ + xx;
#pragma unroll 4
    for (int p = ph; p < 32; p += 2) {
      const float v0 = xp[(2 * p) * (HW_ * HW_)];
      const float v1 = xp[(2 * p + 1) * (HW_ * HW_)];
      l32[xx * 33 + p] = bf16rne(v0) | (bf16rne(v1) << 16);
    }
    __syncthreads();
#pragma unroll 4
    for (int ch = tid; ch < 1024; ch += 256) {  // 128 px * 8 chunks of 8c
      const int px = ch >> 3, qq = ch & 7;
      const unsigned* s = &l32[px * 33 + qq * 4];
      o4[48 + ch] = make_uint4(s[0], s[1], s[2], s[3]);
    }
    return;
  }

  // ---- setup role (tail blocks) ----
  __shared__ int sd[128];
  __shared__ int soffs[C_];
  if (tid < C_) soffs[tid] = offsets[tid];
  __syncthreads();
  if (tid < C_) {  // parallel stable rank sort by (dilation, channel)
    const int key = soffs[tid];
    int rank = 0;
    for (int c = 0; c < C_; ++c) {
      const int kc = soffs[c];
      rank += (int)((kc < key) | ((kc == key) & (c < tid)));
    }
    sd[rank] = tid;
  }
  __syncthreads();
  if (tid == 0) {
    int ni = 0;
    for (int t = 0; t < 2; ++t) {
      int cnt = 0, prev = -1;
      for (int m = 0; m < 32; ++m) {
        const int dd = soffs[sd[t * 32 + m]];
        if (dd != prev && cnt < 6 && ni < MAX_ITEMS) {
          sd[66 + t * 6 + cnt] = dd;
          sd[78 + t * 6 + cnt] = ni;
          sd[91 + ni * 2] = t;
          sd[92 + ni * 2] = dd;
          ++ni;
          ++cnt;
          prev = dd;
        }
      }
      sd[64 + t] = cnt;
    }
    sd[90] = ni;
  }
  __syncthreads();

  const int sbid = bid - nrow;
  if (sbid == 0) {
    if (tid < 91) desc[tid] = sd[tid];
    return;
  }
  const int wix = sbid - 1;
  if (wix >= sd[90]) return;
  const int o = sd[91 + wix * 2];
  const int dit = sd[92 + wix * 2];

  // Pack A-frags: wpack[wix*2304 + ((ks*9+tap)*64+lane)], element layout
  // m = lane&31, k = (lane>>5)*8 + j, ic = ks*16 + k.
  for (int i = tid; i < 4 * 9 * 64; i += 256) {
    const int ks = i / 576;
    const int r = i % 576;
    const int tap = r >> 6;
    const int lane = r & 63;
    const int m = lane & 31, hh = lane >> 5;
    const int oc = sd[o * 32 + m];
    const bool act = (soffs[oc] == dit);  // zero-mask other-dilation rows
    unsigned ww[4];
    for (int jj = 0; jj < 4; ++jj) {
      float v0 = 0.f, v1 = 0.f;
      if (act) {
        const int ic0 = ks * 16 + hh * 8 + jj * 2;
        v0 = w[(oc * C_ + ic0) * 9 + tap];
        v1 = w[(oc * C_ + ic0 + 1) * 9 + tap];
      }
      ww[jj] = bf16rne(v0) | (bf16rne(v1) << 16);
    }
    wpack[(size_t)wix * 2304 + i] = make_uint4(ww[0], ww[1], ww[2], ww[3]);
  }
}

template <bool PRE>
__global__ __launch_bounds__(512, 4) void gsd_conv(
    const float* __restrict__ x, const unsigned short* __restrict__ xb16,
    const int* __restrict__ desc, const uint4* __restrict__ wpack,
    float* __restrict__ out) {
  const int tid = threadIdx.x;
  const int gxid = blockIdx.x;
  const int b = gxid >> 5;
  const int yt = (gxid >> 2) & 7;
  const int xt = gxid & 3;
  const int y0 = yt * 16, x0 = xt * 32;

  const int lane = tid & 63;
  const int n = lane & 31;   // MFMA B col -> output x
  const int h = lane >> 5;   // k-half
  const int wv = tid >> 6;   // 8 waves
  const int o = wv >> 2;     // octile (32 sorted channels)
  const int rq = wv & 3;     // row-quad: y rows rq*4..rq*4+3

  __shared__ __align__(16) unsigned ldsbuf[40 * 256];  // 40960 B, 2 blk/CU

  floatx16 acc[4];
#pragma unroll
  for (int rt = 0; rt < 4; ++rt)
#pragma unroll
    for (int e = 0; e < 16; ++e) acc[rt][e] = 0.f;

  // ---- per-path staging precompute ----
  const unsigned short* xrow;
  int srcoff[5];
  if constexpr (PRE) {
    // Chunk q = (wv + j*8)*64 + lane; LDS dst byte = q*16 (linear).
    // Slot (pix, p) holds logical ic-half p ^ f(pix), f(pix)=(pix>>2)&1
    // (bank swizzle realized via the per-lane global source address).
    xrow = xb16 + (size_t)b * (PADW * PADW * C_);
#pragma unroll
    for (int j = 0; j < 5; ++j) {
      const int q = (wv + j * 8) * 64 + lane;
      int pix = q >> 1;
      if (pix > NPIX - 1) pix = NPIX - 1;  // tail -> LDS pad, src clamped
      const int p = q & 1;
      const int yy = pix / EX, xx = pix - yy * EX;
      const int half = p ^ ((pix >> 2) & 1);
      srcoff[j] = ((y0 + yy) * PADW + (x0 + xx)) * C_ + half * 8;
    }
  }
  int slx, sq, sy2, gxc;
  bool xin;
  const float* xb;
  if constexpr (!PRE) {
    slx = tid & 63;
    sq = (tid >> 6) & 3;
    sy2 = tid >> 8;
    xb = x + (size_t)b * (C_ * HW_ * HW_);
    const int gx = x0 - 6 + slx;
    gxc = gx < 0 ? 0 : (gx > 127 ? 127 : gx);
    xin = ((unsigned)gx < 128u) & (slx < EX);
  }

  const int cnt = __builtin_amdgcn_readfirstlane(desc[64 + o]);

  for (int ks = 0; ks < 4; ++ks) {
    if (ks) __syncthreads();  // protect buffer from overwrite
    if constexpr (PRE) {
      // ---- stage 16 ic: 5 async 16B chunks per wave, zero VALU ----
#pragma unroll
      for (int j = 0; j < 5; ++j) {
        GLOAD_LDS16(xrow + srcoff[j] + ks * 16, &ldsbuf[(wv + j * 8) * 256]);
      }
    } else {
      // ---- stage 16 ic: fp32->bf16 in-kernel (fallback) ----
      const float* xp = xb + (size_t)(ks * 16 + sq * 4) * (HW_ * HW_);
#pragma unroll 2
      for (int yy = sy2; yy < EY; yy += 2) {
        const int gy = y0 - 6 + yy;
        const int gyc = gy < 0 ? 0 : (gy > 127 ? 127 : gy);
        const bool ok = xin & ((unsigned)gy < 128u);
        const float* p = xp + gyc * HW_ + gxc;
        float v0 = p[0];
        float v1 = p[HW_ * HW_];
        float v2 = p[2 * HW_ * HW_];
        float v3 = p[3 * HW_ * HW_];
        if (!ok) { v0 = v1 = v2 = v3 = 0.f; }
        const unsigned lo = bf16rne(v0) | (bf16rne(v1) << 16);
        const unsigned hi = bf16rne(v2) | (bf16rne(v3) << 16);
        if (slx < EX) {
          const int pix = yy * EX + slx;
          const int dws =
              pix * 8 + (((sq >> 1) ^ ((pix >> 2) & 1)) << 2) + ((sq & 1) << 1);
          *reinterpret_cast<uint2*>(&ldsbuf[dws]) = make_uint2(lo, hi);
        }
      }
    }
    __syncthreads();  // (compiler drains vmcnt/lgkmcnt before s_barrier)

    // ---- compute: items of this wave's octile, 9 taps x 4 row-tiles ----
    for (int s = 0; s < cnt; ++s) {
      const int d = __builtin_amdgcn_readfirstlane(desc[66 + o * 6 + s]);
      const int wix = __builtin_amdgcn_readfirstlane(desc[78 + o * 6 + s]);
      const uint4* wp = wpack + ((size_t)wix * 4 + ks) * 576 + lane;
#pragma unroll
      for (int tap = 0; tap < 9; ++tap) {
        const int ky = tap / 3 - 1, kx = tap % 3 - 1;
        const short8 af = __builtin_bit_cast(short8, wp[tap * 64]);
        const int pybase = rq * 4 + ky * d + 6;
        const int pxb = n + kx * d + 6;
#pragma unroll
        for (int rt = 0; rt < 4; ++rt) {
          const int pix = (pybase + rt) * EX + pxb;
          const int dws = (pix << 3) + ((h ^ ((pix >> 2) & 1)) << 2);
          const short8 bf = *reinterpret_cast<const short8*>(&ldsbuf[dws]);
          acc[rt] = __builtin_amdgcn_mfma_f32_32x32x16_bf16(af, bf, acc[rt],
                                                            0, 0, 0);
        }
      }
    }
  }

  // ---- store: D col=lane&31 -> x, row=(reg&3)+8*(reg>>2)+4*h -> oc ----
  int oc[16];
#pragma unroll
  for (int reg = 0; reg < 16; ++reg) {
    const int row = (reg & 3) + 8 * (reg >> 2) + 4 * h;
    oc[reg] = desc[o * 32 + row];
  }
#pragma unroll
  for (int rt = 0; rt < 4; ++rt) {
    const int y = y0 + rq * 4 + rt;
#pragma unroll
    for (int reg = 0; reg < 16; ++reg) {
      out[((size_t)(b * C_ + oc[reg]) * HW_ + y) * HW_ + x0 + n] =
          acc[rt][reg];
    }
  }
}

extern "C" void kernel_launch(void* const* d_in, const int* in_sizes, int n_in,
                              void* d_out, int out_size, void* d_ws,
                              size_t ws_size, hipStream_t stream) {
  const float* x = (const float*)d_in[0];    // [16,64,128,128] fp32
  const float* w = (const float*)d_in[1];    // [64,64,3,3] fp32
  const int* offsets = (const int*)d_in[2];  // [64] int32 in [1,6]
  float* out = (float*)d_out;                // [16,64,128,128] fp32

  int* desc = (int*)d_ws;
  uint4* wpack = (uint4*)((char*)d_ws + WS_WPACK_OFF);  // 442368 B
  unsigned short* xb16 = (unsigned short*)((char*)d_ws + WS_XB16_OFF);

  // Fast path needs 1 MB (desc+wpack) + 40.1 MB (xb16) of workspace.
  const bool pre = ws_size >= (size_t)WS_XB16_OFF + XB16_BYTES;
  const int nrow = pre ? B_ * PADW : 0;

  gsd_prep<<<dim3(nrow + 1 + MAX_ITEMS), 256, 0, stream>>>(
      x, offsets, w, desc, wpack, xb16, nrow);
  if (pre) {
    gsd_conv<true><<<dim3(B_ * 8 * 4), 512, 0, stream>>>(
        x, xb16, desc, wpack, out);
  } else {
    gsd_conv<false><<<dim3(B_ * 8 * 4), 512, 0, stream>>>(
        x, xb16, desc, wpack, out);
  }
}

// Round 3
// 185.082 us; speedup vs baseline: 1.1734x; 1.1734x over previous
//
#include <hip/hip_runtime.h>

// GroupGSDConv round 7: ks-plane layout + 2-phase double-buffered staging.
// Prep writes xb16 as [B][ks=4][140][140][16ch] bf16 (zero-padded, pad=6):
// each ks stage pass now reads DENSE 32B pixel records (wave = 1KB
// contiguous) -> no 64B-granule waste, no inter-pass L2 eviction refetch
// (round-6 FETCH was 159MB ~= 4 passes x 1232px x 64B x 512 blocks).
// Conv: 2-phase pipeline -- STAGE(ks+1) issued before COMPUTE(ks), one
// barrier per ks; staging latency hides under MFMA+ds_read. Two LDS
// buffers of 39936B = 79872B/block -> still 2 blocks/CU (159744 < 160K).
// Chunk tail: waves 0-6 issue 5 gload_lds chunks, wave 7 issues 4 (39
// wave-chunk sets cover 2464 chunks; set 38's upper lanes are src-clamped
// into the 512B pad, never read).
// XCD swizzle: gxid = (bid%8)*64 + bid/8 (512%8==0, bijective) keeps
// halo-sharing neighbor tiles on one XCD's L2.
// Fallback (small ws): in-kernel fp32 staging, single buffer, as round 6.

#define HW_ 128
#define C_ 64
#define B_ 16
#define EX 44
#define EY 28
#define NPIX (EY * EX)              // 1232 staged pixels
#define NCHUNK (NPIX * 2)           // 2464 16B chunks per ks stage
#define NSETS 39                    // ceil(2464/64) wave-chunk sets
#define BUFDW (NSETS * 64 * 4)      // 9984 dwords = 39936 B per buffer
#define PADW 140
#define PLANE_STRIDE (PADW * PADW * 16)  // shorts per ks-plane (313600)
#define MAX_ITEMS 12
#define WS_WPACK_OFF 1024
#define WS_XB16_OFF (1 << 20)
#define XB16_BYTES ((size_t)B_ * 4 * PLANE_STRIDE * 2)  // 40,140,800

// desc layout (ints):
//  [0..63]        perm (sorted-by-dilation channel ids)
//  [64+t]         cnt_t   (items in octile t, t<2)
//  [66+t*6+s]     dilation of item (t,s)
//  [78+t*6+s]     wix (wpack index) of item (t,s)
//  [90]           ni_total

typedef __attribute__((ext_vector_type(8))) short short8;
typedef __attribute__((ext_vector_type(16))) float floatx16;

__device__ __forceinline__ unsigned bf16rne(float f) {
  unsigned u = __float_as_uint(f);
  return (u + 0x7FFFu + ((u >> 16) & 1u)) >> 16;  // round-nearest-even
}

#define GLOAD_LDS16(g, l)                                   \
  __builtin_amdgcn_global_load_lds(                         \
      (const __attribute__((address_space(1))) void*)(g),   \
      (__attribute__((address_space(3))) void*)(l), 16, 0, 0)

__global__ __launch_bounds__(256) void gsd_prep(
    const float* __restrict__ x, const int* __restrict__ offsets,
    const float* __restrict__ w, int* __restrict__ desc,
    uint4* __restrict__ wpack, unsigned short* __restrict__ xb16,
    const int nrow) {
  const int bid = blockIdx.x;
  const int tid = threadIdx.x;

  if (bid < nrow) {
    // ---- transpose+convert one padded row into 4 ks-planes ----
    // per plane-row: 140 px * 16 ch * 2B = 4480 B = 280 uint4 (2/px)
    const int b = bid / PADW, py = bid - b * PADW;
    uint4* o4 = (uint4*)xb16;
    // plane-row base (uint4): plane = 39200 uint4
    const size_t pb0 = ((size_t)b * 4) * 39200 + (size_t)py * 280;
    const uint4 z = make_uint4(0, 0, 0, 0);
    if (py < 6 || py >= PADW - 6) {
      for (int i = tid; i < 1120; i += 256) {
        const int ks = i / 280, r = i - ks * 280;
        o4[pb0 + (size_t)ks * 39200 + r] = z;
      }
      return;
    }
    // x-pads: per plane-row, uint4 0..11 and 268..279
    if (tid < 96) {
      const int ks = tid / 24, rr = tid - ks * 24;
      const int idx = rr < 12 ? rr : 256 + rr;
      o4[pb0 + (size_t)ks * 39200 + idx] = z;
    }
    const int y = py - 6;
    __shared__ unsigned l32[128 * 33];  // [x][c-pair], +1 pad
    const int xx = tid & 127, ph = tid >> 7;
    const float* xp = x + (size_t)b * (C_ * HW_ * HW_) + y * HW_ + xx;
#pragma unroll 4
    for (int p = ph; p < 32; p += 2) {
      const float v0 = xp[(2 * p) * (HW_ * HW_)];
      const float v1 = xp[(2 * p + 1) * (HW_ * HW_)];
      l32[xx * 33 + p] = bf16rne(v0) | (bf16rne(v1) << 16);
    }
    __syncthreads();
#pragma unroll 4
    for (int ch = tid; ch < 1024; ch += 256) {  // 4 planes * 128 px * 2
      const int ks = ch >> 8, r = ch & 255;
      const unsigned* s = &l32[(r >> 1) * 33 + ks * 8 + (r & 1) * 4];
      o4[pb0 + (size_t)ks * 39200 + 12 + r] = make_uint4(s[0], s[1], s[2], s[3]);
    }
    return;
  }

  // ---- setup role (tail blocks) ----
  __shared__ int sd[128];
  __shared__ int soffs[C_];
  if (tid < C_) soffs[tid] = offsets[tid];
  __syncthreads();
  if (tid < C_) {  // parallel stable rank sort by (dilation, channel)
    const int key = soffs[tid];
    int rank = 0;
    for (int c = 0; c < C_; ++c) {
      const int kc = soffs[c];
      rank += (int)((kc < key) | ((kc == key) & (c < tid)));
    }
    sd[rank] = tid;
  }
  __syncthreads();
  if (tid == 0) {
    int ni = 0;
    for (int t = 0; t < 2; ++t) {
      int cnt = 0, prev = -1;
      for (int m = 0; m < 32; ++m) {
        const int dd = soffs[sd[t * 32 + m]];
        if (dd != prev && cnt < 6 && ni < MAX_ITEMS) {
          sd[66 + t * 6 + cnt] = dd;
          sd[78 + t * 6 + cnt] = ni;
          sd[91 + ni * 2] = t;
          sd[92 + ni * 2] = dd;
          ++ni;
          ++cnt;
          prev = dd;
        }
      }
      sd[64 + t] = cnt;
    }
    sd[90] = ni;
  }
  __syncthreads();

  const int sbid = bid - nrow;
  if (sbid == 0) {
    if (tid < 91) desc[tid] = sd[tid];
    return;
  }
  const int wix = sbid - 1;
  if (wix >= sd[90]) return;
  const int o = sd[91 + wix * 2];
  const int dit = sd[92 + wix * 2];

  // Pack A-frags: wpack[wix*2304 + ((ks*9+tap)*64+lane)], element layout
  // m = lane&31, k = (lane>>5)*8 + j, ic = ks*16 + k.
  for (int i = tid; i < 4 * 9 * 64; i += 256) {
    const int ks = i / 576;
    const int r = i % 576;
    const int tap = r >> 6;
    const int lane = r & 63;
    const int m = lane & 31, hh = lane >> 5;
    const int oc = sd[o * 32 + m];
    const bool act = (soffs[oc] == dit);  // zero-mask other-dilation rows
    unsigned ww[4];
    for (int jj = 0; jj < 4; ++jj) {
      float v0 = 0.f, v1 = 0.f;
      if (act) {
        const int ic0 = ks * 16 + hh * 8 + jj * 2;
        v0 = w[(oc * C_ + ic0) * 9 + tap];
        v1 = w[(oc * C_ + ic0 + 1) * 9 + tap];
      }
      ww[jj] = bf16rne(v0) | (bf16rne(v1) << 16);
    }
    wpack[(size_t)wix * 2304 + i] = make_uint4(ww[0], ww[1], ww[2], ww[3]);
  }
}

template <bool PRE>
__global__ __launch_bounds__(512, 4) void gsd_conv(
    const float* __restrict__ x, const unsigned short* __restrict__ xb16,
    const int* __restrict__ desc, const uint4* __restrict__ wpack,
    float* __restrict__ out) {
  const int tid = threadIdx.x;
  const int bid0 = blockIdx.x;
  const int gxid = (bid0 & 7) * 64 + (bid0 >> 3);  // XCD swizzle (512%8==0)
  const int b = gxid >> 5;
  const int yt = (gxid >> 2) & 7;
  const int xt = gxid & 3;
  const int y0 = yt * 16, x0 = xt * 32;

  const int lane = tid & 63;
  const int n = lane & 31;   // MFMA B col -> output x
  const int h = lane >> 5;   // k-half
  const int wv = tid >> 6;   // 8 waves
  const int o = wv >> 2;     // octile (32 sorted channels)
  const int rq = wv & 3;     // row-quad: y rows rq*4..rq*4+3

  __shared__ __align__(16) unsigned ldsbuf[2][BUFDW];  // 79872 B, 2 blk/CU

  floatx16 acc[4];
#pragma unroll
  for (int rt = 0; rt < 4; ++rt)
#pragma unroll
    for (int e = 0; e < 16; ++e) acc[rt][e] = 0.f;

  // ---- per-path staging precompute ----
  const unsigned short* xbase;
  int srcoff[5];
  if constexpr (PRE) {
    // Chunk q = (wv + j*8)*64 + lane; LDS dst byte = q*16 (linear).
    // Slot (pix, p) holds logical ic-half p ^ f(pix), f(pix)=(pix>>2)&1
    // (bank swizzle realized via the per-lane global source address).
    xbase = xb16 + (size_t)b * 4 * PLANE_STRIDE;
#pragma unroll
    for (int j = 0; j < 5; ++j) {
      const int q = (wv + j * 8) * 64 + lane;
      int pix = q >> 1;
      if (pix > NPIX - 1) pix = NPIX - 1;  // set-38 tail -> pad, src clamped
      const int p = q & 1;
      const int yy = pix / EX, xx = pix - yy * EX;
      const int half = p ^ ((pix >> 2) & 1);
      srcoff[j] = ((y0 + yy) * PADW + (x0 + xx)) * 16 + half * 8;
    }
  }
  int slx, sq, sy2, gxc;
  bool xin;
  const float* xb;
  if constexpr (!PRE) {
    slx = tid & 63;
    sq = (tid >> 6) & 3;
    sy2 = tid >> 8;
    xb = x + (size_t)b * (C_ * HW_ * HW_);
    const int gx = x0 - 6 + slx;
    gxc = gx < 0 ? 0 : (gx > 127 ? 127 : gx);
    xin = ((unsigned)gx < 128u) & (slx < EX);
  }

  const int cnt = __builtin_amdgcn_readfirstlane(desc[64 + o]);

  // ---- staging: 5 async 16B chunks/wave (wave 7: 4), zero VALU ----
  auto STAGE = [&](int buf, int ks) {
    if constexpr (PRE) {
      const unsigned short* xp = xbase + (size_t)ks * PLANE_STRIDE;
#pragma unroll
      for (int j = 0; j < 5; ++j) {
        if (j < 4) {
          GLOAD_LDS16(xp + srcoff[j], &ldsbuf[buf][(wv + j * 8) * 256]);
        } else if (wv < 7) {  // sets 32..38 only
          GLOAD_LDS16(xp + srcoff[4], &ldsbuf[buf][(wv + 32) * 256]);
        }
      }
    }
  };

  // ---- compute: items of this wave's octile, 9 taps x 4 row-tiles ----
  auto COMPUTE = [&](const unsigned* cbuf, int ks) {
    for (int s = 0; s < cnt; ++s) {
      const int d = __builtin_amdgcn_readfirstlane(desc[66 + o * 6 + s]);
      const int wix = __builtin_amdgcn_readfirstlane(desc[78 + o * 6 + s]);
      const uint4* wp = wpack + ((size_t)wix * 4 + ks) * 576 + lane;
#pragma unroll
      for (int tap = 0; tap < 9; ++tap) {
        const int ky = tap / 3 - 1, kx = tap % 3 - 1;
        const short8 af = __builtin_bit_cast(short8, wp[tap * 64]);
        const int pybase = rq * 4 + ky * d + 6;
        const int pxb = n + kx * d + 6;
#pragma unroll
        for (int rt = 0; rt < 4; ++rt) {
          const int pix = (pybase + rt) * EX + pxb;
          const int dws = (pix << 3) + ((h ^ ((pix >> 2) & 1)) << 2);
          const short8 bf = *reinterpret_cast<const short8*>(&cbuf[dws]);
          acc[rt] = __builtin_amdgcn_mfma_f32_32x32x16_bf16(af, bf, acc[rt],
                                                            0, 0, 0);
        }
      }
    }
  };

  if constexpr (PRE) {
    // 2-phase pipeline: stage(ks+1) issued before compute(ks); one
    // barrier per ks (drains vmcnt -> staged buffer valid next iter).
    STAGE(0, 0);
    __syncthreads();
#pragma unroll
    for (int ks = 0; ks < 3; ++ks) {
      STAGE((ks + 1) & 1, ks + 1);
      COMPUTE(ldsbuf[ks & 1], ks);
      __syncthreads();
    }
    COMPUTE(ldsbuf[1], 3);
  } else {
    for (int ks = 0; ks < 4; ++ks) {
      if (ks) __syncthreads();
      // fallback: fp32->bf16 in-kernel staging, single buffer
      const float* xp = xb + (size_t)(ks * 16 + sq * 4) * (HW_ * HW_);
#pragma unroll 2
      for (int yy = sy2; yy < EY; yy += 2) {
        const int gy = y0 - 6 + yy;
        const int gyc = gy < 0 ? 0 : (gy > 127 ? 127 : gy);
        const bool ok = xin & ((unsigned)gy < 128u);
        const float* p = xp + gyc * HW_ + gxc;
        float v0 = p[0];
        float v1 = p[HW_ * HW_];
        float v2 = p[2 * HW_ * HW_];
        float v3 = p[3 * HW_ * HW_];
        if (!ok) { v0 = v1 = v2 = v3 = 0.f; }
        const unsigned lo = bf16rne(v0) | (bf16rne(v1) << 16);
        const unsigned hi = bf16rne(v2) | (bf16rne(v3) << 16);
        if (slx < EX) {
          const int pix = yy * EX + slx;
          const int dws =
              pix * 8 + (((sq >> 1) ^ ((pix >> 2) & 1)) << 2) + ((sq & 1) << 1);
          *reinterpret_cast<uint2*>(&ldsbuf[0][dws]) = make_uint2(lo, hi);
        }
      }
      __syncthreads();
      COMPUTE(ldsbuf[0], ks);
    }
  }

  // ---- store: D col=lane&31 -> x, row=(reg&3)+8*(reg>>2)+4*h -> oc ----
  int oc[16];
#pragma unroll
  for (int reg = 0; reg < 16; ++reg) {
    const int row = (reg & 3) + 8 * (reg >> 2) + 4 * h;
    oc[reg] = desc[o * 32 + row];
  }
#pragma unroll
  for (int rt = 0; rt < 4; ++rt) {
    const int y = y0 + rq * 4 + rt;
#pragma unroll
    for (int reg = 0; reg < 16; ++reg) {
      out[((size_t)(b * C_ + oc[reg]) * HW_ + y) * HW_ + x0 + n] =
          acc[rt][reg];
    }
  }
}

extern "C" void kernel_launch(void* const* d_in, const int* in_sizes, int n_in,
                              void* d_out, int out_size, void* d_ws,
                              size_t ws_size, hipStream_t stream) {
  const float* x = (const float*)d_in[0];    // [16,64,128,128] fp32
  const float* w = (const float*)d_in[1];    // [64,64,3,3] fp32
  const int* offsets = (const int*)d_in[2];  // [64] int32 in [1,6]
  float* out = (float*)d_out;                // [16,64,128,128] fp32

  int* desc = (int*)d_ws;
  uint4* wpack = (uint4*)((char*)d_ws + WS_WPACK_OFF);  // 442368 B
  unsigned short* xb16 = (unsigned short*)((char*)d_ws + WS_XB16_OFF);

  // Fast path needs 1 MB (desc+wpack) + 40.1 MB (xb16) of workspace.
  const bool pre = ws_size >= (size_t)WS_XB16_OFF + XB16_BYTES;
  const int nrow = pre ? B_ * PADW : 0;

  gsd_prep<<<dim3(nrow + 1 + MAX_ITEMS), 256, 0, stream>>>(
      x, offsets, w, desc, wpack, xb16, nrow);
  if (pre) {
    gsd_conv<true><<<dim3(B_ * 8 * 4), 512, 0, stream>>>(
        x, xb16, desc, wpack, out);
  } else {
    gsd_conv<false><<<dim3(B_ * 8 * 4), 512, 0, stream>>>(
        x, xb16, desc, wpack, out);
  }
}